// Round 15
// baseline (442.577 us; speedup 1.0000x reference)
//
#include <hip/hip_runtime.h>
#include <hip/hip_fp16.h>

#define DT 0.1f
#define NSTEPS 10

typedef float f4 __attribute__((ext_vector_type(4)));
typedef __fp16 h2 __attribute__((ext_vector_type(2)));
typedef __fp16 h4 __attribute__((ext_vector_type(4)));

// MFMA builtin exists only in the device pass; host pass just needs to parse.
#if defined(__HIP_DEVICE_COMPILE__)
  #if __has_builtin(__builtin_amdgcn_mfma_f32_16x16x16f16)
    #define MFMA16(A, B, C) __builtin_amdgcn_mfma_f32_16x16x16f16((A), (B), (C), 0, 0, 0)
  #else
    #define MFMA16(A, B, C) __builtin_amdgcn_mfma_f32_16x16x16_f16((A), (B), (C), 0, 0, 0)
  #endif
  #define SQRTF(x) __builtin_amdgcn_sqrtf(x)
#else
  // host pass only needs a well-typed expression; never executed
  #define MFMA16(A, B, C) ((void)(A), (void)(B), (C))
  #define SQRTF(x) sqrtf(x)
#endif

// Packed-f16 tanh (validated R10/R11): tanh(x) = 1 - 2/(exp2(k*x)+1).
// NaN-free saturation in f16.
static __device__ __forceinline__ __half2 tanh2(__half2 z) {
    const __half2 kk   = __float2half2_rn(2.8853900818f);
    const __half2 one  = __float2half2_rn(1.0f);
    const __half2 mtwo = __float2half2_rn(-2.0f);
    __half2 e = h2exp2(__hmul2(z, kk));
    __half2 r = h2rcp(__hadd2(e, one));
    return __hfma2(r, mtwo, one);
}

// tanh on a 4-f32 MFMA accumulator -> 4 halves, laid out ready as the next
// MFMA's B operand (D row index == next B k index, same lane/reg structure).
static __device__ __forceinline__ h4 act_h4(f4 d) {
    __half2 a = __floats2half2_rn(d[0], d[1]);   // low = d[0]
    __half2 b = __floats2half2_rn(d[2], d[3]);
    h2 ta = __builtin_bit_cast(h2, tanh2(a));
    h2 tb = __builtin_bit_cast(h2, tanh2(b));
    h4 r;
    r[0] = ta[0]; r[1] = ta[1]; r[2] = tb[0]; r[3] = tb[1];
    return r;
}

__global__ void __launch_bounds__(256) rollout_kernel(
    const float* __restrict__ s_star, const float* __restrict__ s0,
    const float* __restrict__ fc1_w, const float* __restrict__ fc1_b,
    const float* __restrict__ fc2_w, const float* __restrict__ fc2_b,
    const float* __restrict__ rc1_w, const float* __restrict__ rc1_b,
    const float* __restrict__ rc2_w, const float* __restrict__ rc2_b,
    const float* __restrict__ rc3_w, const float* __restrict__ rc3_b,
    const float* __restrict__ rr1_w, const float* __restrict__ rr1_b,
    const float* __restrict__ rr2_w, const float* __restrict__ rr2_b,
    const float* __restrict__ rr3_w, const float* __restrict__ rr3_b,
    float* __restrict__ out, int NCHUNK)  // NCHUNK = B/16
{
    int lane = threadIdx.x & 63;
    int wid  = threadIdx.x >> 6;
    int chunk = blockIdx.x * 4 + wid;     // one 16-row chunk per wave
    if (chunk >= NCHUNK) return;

    int col = lane & 15;                  // batch column within chunk
    int kg  = lane >> 4;                  // k/row group 0..3
    int row = chunk * 16 + col;           // global batch row

    // ---- uniform fused predictor: ah = A @ [s, s_star] + cb ----
    float A[2][4];
    float cb[2];
#pragma unroll
    for (int r = 0; r < 2; ++r) {
#pragma unroll
        for (int c = 0; c < 4; ++c) {
            float a = 0.0f;
#pragma unroll
            for (int j = 0; j < 4; ++j)
                a = fmaf(fc2_w[r * 4 + j], fc1_w[j * 4 + c], a);
            A[r][c] = a;
        }
        float b = fc2_b[r];
#pragma unroll
        for (int j = 0; j < 4; ++j) b = fmaf(fc2_w[r * 4 + j], fc1_b[j], b);
        cb[r] = b;
    }

    // ---- per-col state ----
    float2 ssv = reinterpret_cast<const float2*>(s_star)[row];
    float2 s0v = reinterpret_cast<const float2*>(s0)[row];
    float ssx = ssv.x, ssy = ssv.y;
    float sx = s0v.x, sy = s0v.y;
    float d0 = fmaf(A[0][2], ssx, fmaf(A[0][3], ssy, cb[0]));
    float d1 = fmaf(A[1][2], ssx, fmaf(A[1][3], ssy, cb[1]));
    float ahs0 = (ssx > 0.5f) ? -1.0f : 1.0f;

    const __fp16 hz = (__fp16)0.0f;

    // ---- A1: folded layer-1 M (rows 0-7 = rr, 8-15 = rc), K used = 2 ----
    // A[row][k]: lane holds row=lane&15, k=4*kg+j. Only k=0,1 nonzero.
    int r = col;            // fragment row index (numerically lane&15)
    int jr = r & 7;
    const float* w1p = (r < 8) ? rr1_w : rc1_w;
    float w12 = w1p[jr * 4 + 2], w13 = w1p[jr * 4 + 3];
    float m0 = fmaf(w12, A[0][0], fmaf(w13, A[1][0], w1p[jr * 4 + 0]));
    float m1 = fmaf(w12, A[0][1], fmaf(w13, A[1][1], w1p[jr * 4 + 1]));
    bool b1on = (kg == 0);
    h4 A1;
    A1[0] = b1on ? (__fp16)m0 : hz;
    A1[1] = b1on ? (__fp16)m1 : hz;
    A1[2] = hz;
    A1[3] = hz;

    // ---- A2: block-diag(W2rr, W2rc) ----
    h4 A2;
#pragma unroll
    for (int j = 0; j < 4; ++j) {
        int k = 4 * kg + j;
        float v = 0.0f;
        if (r < 8) { if (k < 8) v = rr2_w[r * 8 + k]; }
        else       { if (k >= 8) v = rc2_w[(r - 8) * 8 + (k - 8)]; }
        A2[j] = (__fp16)v;
    }

    // ---- A3: rows 0,1 = W3rr (k<8); rows 2,3 = W3rc (k>=8) ----
    h4 A3;
#pragma unroll
    for (int j = 0; j < 4; ++j) {
        int k = 4 * kg + j;
        float v = 0.0f;
        if (r < 2)      { if (k < 8)  v = rr3_w[r * 8 + k]; }
        else if (r < 4) { if (k >= 8) v = rc3_w[(r - 2) * 8 + (k - 8)]; }
        A3[j] = (__fp16)v;
    }

    // ---- C operands (f32 accumulators; C/D row = 4*kg+reg, col = lane&15) ----
    f4 C1, C2, C3;
#pragma unroll
    for (int j = 0; j < 4; ++j) {
        int cr = 4 * kg + j;
        const float* wq = (cr < 8) ? rr1_w : rc1_w;
        const float* bq = (cr < 8) ? rr1_b : rc1_b;
        int jq = cr & 7;
        C1[j] = fmaf(wq[jq * 4 + 2], d0, fmaf(wq[jq * 4 + 3], d1, bq[jq]));
        C2[j] = (cr < 8) ? rr2_b[cr] : rc2_b[cr - 8];
        C3[j] = (cr < 2) ? rr3_b[cr] : ((cr < 4) ? rc3_b[cr - 2] : 0.0f);
    }

    float err = 0.0f;

#pragma unroll 1
    for (int t = 0; t < NSTEPS; ++t) {
        // B1: s for this col at k=0,1 (kg==0 lanes); zero elsewhere
        h4 B1;
        B1[0] = b1on ? (__fp16)sx : hz;
        B1[1] = b1on ? (__fp16)sy : hz;
        B1[2] = hz;
        B1[3] = hz;

        f4 D1 = MFMA16(A1, B1, C1);      // z1 (rows 0-7 rr, 8-15 rc)
        h4 B2 = act_h4(D1);              // h = tanh(z1), ready as B
        f4 D2 = MFMA16(A2, B2, C2);      // z2
        h4 B3 = act_h4(D2);              // g = tanh(z2)
        f4 D3 = MFMA16(A3, B3, C3);      // rows 0..3 = arr0,arr1,ar0,ar1

        float ah0 = fmaf(A[0][0], sx, fmaf(A[0][1], sy, d0));
        float ah1 = fmaf(A[1][0], sx, fmaf(A[1][1], sy, d1));

        sx = fmaf(DT, D3[2], sx);        // ar0
        sy = fmaf(DT, D3[3], sy);        // ar1

        float dx = ssx - sx, dy = ssy - sy;
        float n1 = fmaf(dx, dx, dy * dy);
        float ux = D3[0] - D3[2], uy = D3[1] - D3[3];
        float n2 = fmaf(ux, ux, uy * uy);
        float vx = ahs0 - ah0;
        float n3 = fmaf(vx, vx, ah1 * ah1);

        err = err + SQRTF(n1);
        err = fmaf(0.1f, SQRTF(n2), err);
        err = err + SQRTF(n3);
    }

    if (lane < 16) out[row] = err;
}

extern "C" void kernel_launch(void* const* d_in, const int* in_sizes, int n_in,
                              void* d_out, int out_size, void* d_ws, size_t ws_size,
                              hipStream_t stream) {
    const float* s_star = (const float*)d_in[0];
    const float* s0     = (const float*)d_in[1];
    const float* fc1_w  = (const float*)d_in[2];
    const float* fc1_b  = (const float*)d_in[3];
    const float* fc2_w  = (const float*)d_in[4];
    const float* fc2_b  = (const float*)d_in[5];
    const float* rc1_w  = (const float*)d_in[6];
    const float* rc1_b  = (const float*)d_in[7];
    const float* rc2_w  = (const float*)d_in[8];
    const float* rc2_b  = (const float*)d_in[9];
    const float* rc3_w  = (const float*)d_in[10];
    const float* rc3_b  = (const float*)d_in[11];
    const float* rr1_w  = (const float*)d_in[12];
    const float* rr1_b  = (const float*)d_in[13];
    const float* rr2_w  = (const float*)d_in[14];
    const float* rr2_b  = (const float*)d_in[15];
    const float* rr3_w  = (const float*)d_in[16];
    const float* rr3_b  = (const float*)d_in[17];
    float* out = (float*)d_out;

    int B = in_sizes[0] / 2;       // rows (4194304)
    int NCHUNK = B / 16;           // 16-row chunks, one per wave
    int block = 256;               // 4 waves -> 4 chunks per block
    int grid = (NCHUNK + 3) / 4;
    rollout_kernel<<<grid, block, 0, stream>>>(
        s_star, s0, fc1_w, fc1_b, fc2_w, fc2_b,
        rc1_w, rc1_b, rc2_w, rc2_b, rc3_w, rc3_b,
        rr1_w, rr1_b, rr2_w, rr2_b, rr3_w, rr3_b,
        out, NCHUNK);
}

// Round 16
// 346.602 us; speedup vs baseline: 1.2769x; 1.2769x over previous
//
#include <hip/hip_runtime.h>
#include <hip/hip_fp16.h>

#define DT 0.1f
#define NSTEPS 10

typedef float f4 __attribute__((ext_vector_type(4)));
typedef __fp16 h2 __attribute__((ext_vector_type(2)));
typedef __fp16 h4 __attribute__((ext_vector_type(4)));

// MFMA builtin exists only in the device pass; host pass just needs to parse.
#if defined(__HIP_DEVICE_COMPILE__)
  #if __has_builtin(__builtin_amdgcn_mfma_f32_16x16x16f16)
    #define MFMA16(A, B, C) __builtin_amdgcn_mfma_f32_16x16x16f16((A), (B), (C), 0, 0, 0)
  #else
    #define MFMA16(A, B, C) __builtin_amdgcn_mfma_f32_16x16x16_f16((A), (B), (C), 0, 0, 0)
  #endif
  #define SQRTF(x) __builtin_amdgcn_sqrtf(x)
#else
  #define MFMA16(A, B, C) ((void)(A), (void)(B), (C))
  #define SQRTF(x) sqrtf(x)
#endif

// Packed-f16 tanh (validated R10/R11/R15): tanh(x) = 1 - 2/(exp2(k*x)+1).
// NaN-free saturation in f16.
static __device__ __forceinline__ __half2 tanh2(__half2 z) {
    const __half2 kk   = __float2half2_rn(2.8853900818f);
    const __half2 one  = __float2half2_rn(1.0f);
    const __half2 mtwo = __float2half2_rn(-2.0f);
    __half2 e = h2exp2(__hmul2(z, kk));
    __half2 r = h2rcp(__hadd2(e, one));
    return __hfma2(r, mtwo, one);
}

// tanh on a 4-f32 MFMA accumulator -> 4 halves, laid out ready as the next
// MFMA's B operand (D row index == next B k index, same lane/reg structure).
static __device__ __forceinline__ h4 act_h4(f4 d) {
    __half2 a = __floats2half2_rn(d[0], d[1]);   // low = d[0]
    __half2 b = __floats2half2_rn(d[2], d[3]);
    h2 ta = __builtin_bit_cast(h2, tanh2(a));
    h2 tb = __builtin_bit_cast(h2, tanh2(b));
    h4 r;
    r[0] = ta[0]; r[1] = ta[1]; r[2] = tb[0]; r[3] = tb[1];
    return r;
}

__global__ void __launch_bounds__(256) rollout_kernel(
    const float* __restrict__ s_star, const float* __restrict__ s0,
    const float* __restrict__ fc1_w, const float* __restrict__ fc1_b,
    const float* __restrict__ fc2_w, const float* __restrict__ fc2_b,
    const float* __restrict__ rc1_w, const float* __restrict__ rc1_b,
    const float* __restrict__ rc2_w, const float* __restrict__ rc2_b,
    const float* __restrict__ rc3_w, const float* __restrict__ rc3_b,
    const float* __restrict__ rr1_w, const float* __restrict__ rr1_b,
    const float* __restrict__ rr2_w, const float* __restrict__ rr2_b,
    const float* __restrict__ rr3_w, const float* __restrict__ rr3_b,
    float* __restrict__ out, int NW)   // NW = B/64 waves
{
    int lane = threadIdx.x & 63;
    int wid  = threadIdx.x >> 6;
    int wave = blockIdx.x * 4 + wid;
    if (wave >= NW) return;

    int col = lane & 15;                // batch column within each 16-row chunk
    int kg  = lane >> 4;                // k-group / chunk ownership 0..3
    int rA  = col;                      // A-fragment row for this lane
    int row = wave * 64 + lane;         // this lane's own batch row (chunk kg, col)

    // ---- uniform fused predictor: ah = A @ [s, s_star] + cb ----
    float A[2][4];
    float cb[2];
#pragma unroll
    for (int r = 0; r < 2; ++r) {
#pragma unroll
        for (int c = 0; c < 4; ++c) {
            float a = 0.0f;
#pragma unroll
            for (int j = 0; j < 4; ++j)
                a = fmaf(fc2_w[r * 4 + j], fc1_w[j * 4 + c], a);
            A[r][c] = a;
        }
        float b = fc2_b[r];
#pragma unroll
        for (int j = 0; j < 4; ++j) b = fmaf(fc2_w[r * 4 + j], fc1_b[j], b);
        cb[r] = b;
    }

    // ---- per-lane (own-row) state ----
    float2 ssv = reinterpret_cast<const float2*>(s_star)[row];
    float2 s0v = reinterpret_cast<const float2*>(s0)[row];
    float ssx = ssv.x, ssy = ssv.y;
    float sx = s0v.x, sy = s0v.y;
    float d0 = fmaf(A[0][2], ssx, fmaf(A[0][3], ssy, cb[0]));
    float d1 = fmaf(A[1][2], ssx, fmaf(A[1][3], ssy, cb[1]));
    float ahs0 = (ssx > 0.5f) ? -1.0f : 1.0f;

    h4 zero4; zero4[0] = (__fp16)0.0f; zero4[1] = (__fp16)0.0f;
    zero4[2] = (__fp16)0.0f; zero4[3] = (__fp16)0.0f;

    // ---- A1: raw W1 rows (0-7 rr, 8-15 rc); same 4 values for every kg,
    // since chunk q's input occupies k = 4q+j and W1 repeats per chunk. ----
    int jr = rA & 7;
    const float* w1p = (rA < 8) ? rr1_w : rc1_w;
    h4 A1;
#pragma unroll
    for (int j = 0; j < 4; ++j) A1[j] = (__fp16)w1p[jr * 4 + j];

    // ---- A2: block-diag(W2rr, W2rc), shared by all chunks ----
    h4 A2;
#pragma unroll
    for (int j = 0; j < 4; ++j) {
        int k = 4 * kg + j;
        float v = 0.0f;
        if (rA < 8) { if (k < 8) v = rr2_w[rA * 8 + k]; }
        else        { if (k >= 8) v = rc2_w[(rA - 8) * 8 + (k - 8)]; }
        A2[j] = (__fp16)v;
    }

    // ---- A3: per-chunk fragments. Chunk q's outputs occupy rows 4q..4q+3:
    //   row 4q+0: arr0 = W3rr[0]  (k<8) ; 4q+1: arr1 = W3rr[1] (k<8)
    //   row 4q+2: ar0  = W3rc[0] (k>=8); 4q+3: ar1  = W3rc[1] (k>=8)
    // Each lane's A-row rA is nonzero for exactly one chunk q* = rA>>2. ----
    int qstar = rA >> 2;
    int o = rA & 3;
    h4 A3own;
#pragma unroll
    for (int j = 0; j < 4; ++j) {
        int k = 4 * kg + j;
        float v = 0.0f;
        if (o < 2) { if (k < 8)  v = rr3_w[o * 8 + k]; }
        else       { if (k >= 8) v = rc3_w[(o - 2) * 8 + (k - 8)]; }
        A3own[j] = (__fp16)v;
    }
    h4 A3f0 = (qstar == 0) ? A3own : zero4;
    h4 A3f1 = (qstar == 1) ? A3own : zero4;
    h4 A3f2 = (qstar == 2) ? A3own : zero4;
    h4 A3f3 = (qstar == 3) ? A3own : zero4;

    // ---- C operands (f32; C/D row = 4*kg+reg, col = lane&15) ----
    f4 C1, C2, C3;
#pragma unroll
    for (int j = 0; j < 4; ++j) {
        int r4 = 4 * kg + j;
        C1[j] = (r4 < 8) ? rr1_b[r4] : rc1_b[r4 - 8];
        C2[j] = (r4 < 8) ? rr2_b[r4] : rc2_b[r4 - 8];
    }
    C3[0] = rr3_b[0]; C3[1] = rr3_b[1]; C3[2] = rc3_b[0]; C3[3] = rc3_b[1];

    float err = 0.0f;

#pragma unroll 1
    for (int t = 0; t < NSTEPS; ++t) {
        float ah0 = fmaf(A[0][0], sx, fmaf(A[0][1], sy, d0));
        float ah1 = fmaf(A[1][0], sx, fmaf(A[1][1], sy, d1));

        // own-state L1 input, masked to this lane's chunk slot
        h4 Bown;
        Bown[0] = (__fp16)sx;  Bown[1] = (__fp16)sy;
        Bown[2] = (__fp16)ah0; Bown[3] = (__fp16)ah1;
        h4 B1_0 = (kg == 0) ? Bown : zero4;
        h4 B1_1 = (kg == 1) ? Bown : zero4;
        h4 B1_2 = (kg == 2) ? Bown : zero4;
        h4 B1_3 = (kg == 3) ? Bown : zero4;

        // L1 (4 independent chains)
        f4 D1_0 = MFMA16(A1, B1_0, C1);
        f4 D1_1 = MFMA16(A1, B1_1, C1);
        f4 D1_2 = MFMA16(A1, B1_2, C1);
        f4 D1_3 = MFMA16(A1, B1_3, C1);
        h4 B2_0 = act_h4(D1_0);
        h4 B2_1 = act_h4(D1_1);
        h4 B2_2 = act_h4(D1_2);
        h4 B2_3 = act_h4(D1_3);

        // L2
        f4 D2_0 = MFMA16(A2, B2_0, C2);
        f4 D2_1 = MFMA16(A2, B2_1, C2);
        f4 D2_2 = MFMA16(A2, B2_2, C2);
        f4 D2_3 = MFMA16(A2, B2_3, C2);
        h4 B3_0 = act_h4(D2_0);
        h4 B3_1 = act_h4(D2_1);
        h4 B3_2 = act_h4(D2_2);
        h4 B3_3 = act_h4(D2_3);

        // L3: accumulate all chunks into one D3 (disjoint rows): lane's regs
        // 0..3 end up holding rows 4*kg..4*kg+3 = its own chunk's outputs.
        f4 D3 = MFMA16(A3f0, B3_0, C3);
        D3 = MFMA16(A3f1, B3_1, D3);
        D3 = MFMA16(A3f2, B3_2, D3);
        D3 = MFMA16(A3f3, B3_3, D3);

        float arr0 = D3[0], arr1 = D3[1], ar0 = D3[2], ar1 = D3[3];

        sx = fmaf(DT, ar0, sx);
        sy = fmaf(DT, ar1, sy);

        float dx = ssx - sx, dy = ssy - sy;
        float n1 = fmaf(dx, dx, dy * dy);
        float ux = arr0 - ar0, uy = arr1 - ar1;
        float n2 = fmaf(ux, ux, uy * uy);
        float vx = ahs0 - ah0;
        float n3 = fmaf(vx, vx, ah1 * ah1);

        err = err + SQRTF(n1);
        err = fmaf(0.1f, SQRTF(n2), err);
        err = err + SQRTF(n3);
    }

    out[row] = err;   // full-wave coalesced store
}

extern "C" void kernel_launch(void* const* d_in, const int* in_sizes, int n_in,
                              void* d_out, int out_size, void* d_ws, size_t ws_size,
                              hipStream_t stream) {
    const float* s_star = (const float*)d_in[0];
    const float* s0     = (const float*)d_in[1];
    const float* fc1_w  = (const float*)d_in[2];
    const float* fc1_b  = (const float*)d_in[3];
    const float* fc2_w  = (const float*)d_in[4];
    const float* fc2_b  = (const float*)d_in[5];
    const float* rc1_w  = (const float*)d_in[6];
    const float* rc1_b  = (const float*)d_in[7];
    const float* rc2_w  = (const float*)d_in[8];
    const float* rc2_b  = (const float*)d_in[9];
    const float* rc3_w  = (const float*)d_in[10];
    const float* rc3_b  = (const float*)d_in[11];
    const float* rr1_w  = (const float*)d_in[12];
    const float* rr1_b  = (const float*)d_in[13];
    const float* rr2_w  = (const float*)d_in[14];
    const float* rr2_b  = (const float*)d_in[15];
    const float* rr3_w  = (const float*)d_in[16];
    const float* rr3_b  = (const float*)d_in[17];
    float* out = (float*)d_out;

    int B = in_sizes[0] / 2;       // rows (4194304)
    int NW = B / 64;               // 64 rows per wave
    int block = 256;               // 4 waves per block
    int grid = (NW + 3) / 4;
    rollout_kernel<<<grid, block, 0, stream>>>(
        s_star, s0, fc1_w, fc1_b, fc2_w, fc2_b,
        rc1_w, rc1_b, rc2_w, rc2_b, rc3_w, rc3_b,
        rr1_w, rr1_b, rr2_w, rr2_b, rr3_w, rr3_b,
        out, NW);
}

// Round 17
// 334.727 us; speedup vs baseline: 1.3222x; 1.0355x over previous
//
#include <hip/hip_runtime.h>
#include <hip/hip_fp16.h>

#define DT 0.1f
#define NSTEPS 10

typedef float f4 __attribute__((ext_vector_type(4)));
typedef __fp16 h2 __attribute__((ext_vector_type(2)));
typedef __fp16 h4 __attribute__((ext_vector_type(4)));

// MFMA builtin exists only in the device pass; host pass just needs to parse.
#if defined(__HIP_DEVICE_COMPILE__)
  #if __has_builtin(__builtin_amdgcn_mfma_f32_16x16x16f16)
    #define MFMA16(A, B, C) __builtin_amdgcn_mfma_f32_16x16x16f16((A), (B), (C), 0, 0, 0)
  #else
    #define MFMA16(A, B, C) __builtin_amdgcn_mfma_f32_16x16x16_f16((A), (B), (C), 0, 0, 0)
  #endif
  #define SQRTF(x) __builtin_amdgcn_sqrtf(x)
#else
  #define MFMA16(A, B, C) ((void)(A), (void)(B), (C))
  #define SQRTF(x) sqrtf(x)
#endif

// Packed-f16 tanh (validated R10-R16): tanh(x) = 1 - 2/(exp2(k*x)+1).
// NaN-free saturation in f16.
static __device__ __forceinline__ __half2 tanh2(__half2 z) {
    const __half2 kk   = __float2half2_rn(2.8853900818f);
    const __half2 one  = __float2half2_rn(1.0f);
    const __half2 mtwo = __float2half2_rn(-2.0f);
    __half2 e = h2exp2(__hmul2(z, kk));
    __half2 r = h2rcp(__hadd2(e, one));
    return __hfma2(r, mtwo, one);
}

// tanh on a 4-f32 MFMA accumulator -> 4 halves, laid out ready as the next
// MFMA's B operand (D row index == next B k index, same lane/reg structure).
static __device__ __forceinline__ h4 act_h4(f4 d) {
    __half2 a = __floats2half2_rn(d[0], d[1]);   // low = d[0]
    __half2 b = __floats2half2_rn(d[2], d[3]);
    h2 ta = __builtin_bit_cast(h2, tanh2(a));
    h2 tb = __builtin_bit_cast(h2, tanh2(b));
    h4 r;
    r[0] = ta[0]; r[1] = ta[1]; r[2] = tb[0]; r[3] = tb[1];
    return r;
}

__global__ void __launch_bounds__(256) rollout_kernel(
    const float* __restrict__ s_star, const float* __restrict__ s0,
    const float* __restrict__ fc1_w, const float* __restrict__ fc1_b,
    const float* __restrict__ fc2_w, const float* __restrict__ fc2_b,
    const float* __restrict__ rc1_w, const float* __restrict__ rc1_b,
    const float* __restrict__ rc2_w, const float* __restrict__ rc2_b,
    const float* __restrict__ rc3_w, const float* __restrict__ rc3_b,
    const float* __restrict__ rr1_w, const float* __restrict__ rr1_b,
    const float* __restrict__ rr2_w, const float* __restrict__ rr2_b,
    const float* __restrict__ rr3_w, const float* __restrict__ rr3_b,
    float* __restrict__ out, int NW)   // NW = B/128 waves
{
    int lane = threadIdx.x & 63;
    int wid  = threadIdx.x >> 6;
    int wave = blockIdx.x * 4 + wid;
    if (wave >= NW) return;

    int col = lane & 15;                // batch column within each 16-row chunk
    int kg  = lane >> 4;                // k-group / chunk ownership 0..3
    int rA  = col;                      // A-fragment row for this lane
    int rowA = wave * 128 + lane;       // set 0 row
    int rowB = rowA + 64;               // set 1 row

    // ---- uniform fused predictor: ah = A @ [s, s_star] + cb ----
    float A[2][4];
    float cb[2];
#pragma unroll
    for (int r = 0; r < 2; ++r) {
#pragma unroll
        for (int c = 0; c < 4; ++c) {
            float a = 0.0f;
#pragma unroll
            for (int j = 0; j < 4; ++j)
                a = fmaf(fc2_w[r * 4 + j], fc1_w[j * 4 + c], a);
            A[r][c] = a;
        }
        float b = fc2_b[r];
#pragma unroll
        for (int j = 0; j < 4; ++j) b = fmaf(fc2_w[r * 4 + j], fc1_b[j], b);
        cb[r] = b;
    }

    // ---- per-lane state, 2 row-sets ----
    float ssx[2], ssy[2], sx[2], sy[2], d0[2], d1[2], ahs0[2], err[2];
    {
        float2 sA = reinterpret_cast<const float2*>(s_star)[rowA];
        float2 sB = reinterpret_cast<const float2*>(s_star)[rowB];
        float2 vA = reinterpret_cast<const float2*>(s0)[rowA];
        float2 vB = reinterpret_cast<const float2*>(s0)[rowB];
        ssx[0] = sA.x; ssy[0] = sA.y; sx[0] = vA.x; sy[0] = vA.y;
        ssx[1] = sB.x; ssy[1] = sB.y; sx[1] = vB.x; sy[1] = vB.y;
    }
#pragma unroll
    for (int s = 0; s < 2; ++s) {
        d0[s] = fmaf(A[0][2], ssx[s], fmaf(A[0][3], ssy[s], cb[0]));
        d1[s] = fmaf(A[1][2], ssx[s], fmaf(A[1][3], ssy[s], cb[1]));
        ahs0[s] = (ssx[s] > 0.5f) ? -1.0f : 1.0f;
        err[s] = 0.0f;
    }

    h4 zero4; zero4[0] = (__fp16)0.0f; zero4[1] = (__fp16)0.0f;
    zero4[2] = (__fp16)0.0f; zero4[3] = (__fp16)0.0f;

    // ---- A1: raw W1 rows (0-7 rr, 8-15 rc), masked per chunk (LOOP-INVARIANT).
    // Chunk q uses k-slots 4q..4q+3; lane supplies A1 only when kg==q, so the
    // unmasked own-state B fragment contributes only its own chunk's input. ----
    int jr = rA & 7;
    const float* w1p = (rA < 8) ? rr1_w : rc1_w;
    h4 A1raw;
#pragma unroll
    for (int j = 0; j < 4; ++j) A1raw[j] = (__fp16)w1p[jr * 4 + j];
    h4 A1m[4];
#pragma unroll
    for (int q = 0; q < 4; ++q) A1m[q] = (kg == q) ? A1raw : zero4;

    // ---- A2: block-diag(W2rr, W2rc), shared by all chunks ----
    h4 A2;
#pragma unroll
    for (int j = 0; j < 4; ++j) {
        int k = 4 * kg + j;
        float v = 0.0f;
        if (rA < 8) { if (k < 8) v = rr2_w[rA * 8 + k]; }
        else        { if (k >= 8) v = rc2_w[(rA - 8) * 8 + (k - 8)]; }
        A2[j] = (__fp16)v;
    }

    // ---- A3: per-chunk fragments (chunk q outputs -> rows 4q..4q+3) ----
    int qstar = rA >> 2;
    int o = rA & 3;
    h4 A3own;
#pragma unroll
    for (int j = 0; j < 4; ++j) {
        int k = 4 * kg + j;
        float v = 0.0f;
        if (o < 2) { if (k < 8)  v = rr3_w[o * 8 + k]; }
        else       { if (k >= 8) v = rc3_w[(o - 2) * 8 + (k - 8)]; }
        A3own[j] = (__fp16)v;
    }
    h4 A3f[4];
#pragma unroll
    for (int q = 0; q < 4; ++q) A3f[q] = (qstar == q) ? A3own : zero4;

    // ---- C operands (f32; C/D row = 4*kg+reg, col = lane&15) ----
    f4 C1, C2, C3;
#pragma unroll
    for (int j = 0; j < 4; ++j) {
        int r4 = 4 * kg + j;
        C1[j] = (r4 < 8) ? rr1_b[r4] : rc1_b[r4 - 8];
        C2[j] = (r4 < 8) ? rr2_b[r4] : rc2_b[r4 - 8];
    }
    C3[0] = rr3_b[0]; C3[1] = rr3_b[1]; C3[2] = rc3_b[0]; C3[3] = rc3_b[1];

#pragma unroll 1
    for (int t = 0; t < NSTEPS; ++t) {
        float ah0[2], ah1[2];
        h4 Bown[2];
#pragma unroll
        for (int s = 0; s < 2; ++s) {
            ah0[s] = fmaf(A[0][0], sx[s], fmaf(A[0][1], sy[s], d0[s]));
            ah1[s] = fmaf(A[1][0], sx[s], fmaf(A[1][1], sy[s], d1[s]));
            Bown[s][0] = (__fp16)sx[s];
            Bown[s][1] = (__fp16)sy[s];
            Bown[s][2] = (__fp16)ah0[s];
            Bown[s][3] = (__fp16)ah1[s];
        }

        // L1: 8 independent MFMAs (A-masked, unmasked own-state B)
        h4 B2[2][4];
#pragma unroll
        for (int s = 0; s < 2; ++s) {
#pragma unroll
            for (int q = 0; q < 4; ++q) {
                f4 D1 = MFMA16(A1m[q], Bown[s], C1);
                B2[s][q] = act_h4(D1);
            }
        }

        // L2: 8 independent MFMAs
        h4 B3[2][4];
#pragma unroll
        for (int s = 0; s < 2; ++s) {
#pragma unroll
            for (int q = 0; q < 4; ++q) {
                f4 D2 = MFMA16(A2, B2[s][q], C2);
                B3[s][q] = act_h4(D2);
            }
        }

        // L3: per-set accumulator chain over disjoint row-blocks
#pragma unroll
        for (int s = 0; s < 2; ++s) {
            f4 D3 = MFMA16(A3f[0], B3[s][0], C3);
            D3 = MFMA16(A3f[1], B3[s][1], D3);
            D3 = MFMA16(A3f[2], B3[s][2], D3);
            D3 = MFMA16(A3f[3], B3[s][3], D3);

            float arr0 = D3[0], arr1 = D3[1], ar0 = D3[2], ar1 = D3[3];

            sx[s] = fmaf(DT, ar0, sx[s]);
            sy[s] = fmaf(DT, ar1, sy[s]);

            float dx = ssx[s] - sx[s], dy = ssy[s] - sy[s];
            float n1 = fmaf(dx, dx, dy * dy);
            float ux = arr0 - ar0, uy = arr1 - ar1;
            float n2 = fmaf(ux, ux, uy * uy);
            float vx = ahs0[s] - ah0[s];
            float n3 = fmaf(vx, vx, ah1[s] * ah1[s]);

            err[s] = err[s] + SQRTF(n1);
            err[s] = fmaf(0.1f, SQRTF(n2), err[s]);
            err[s] = err[s] + SQRTF(n3);
        }
    }

    out[rowA] = err[0];
    out[rowB] = err[1];
}

extern "C" void kernel_launch(void* const* d_in, const int* in_sizes, int n_in,
                              void* d_out, int out_size, void* d_ws, size_t ws_size,
                              hipStream_t stream) {
    const float* s_star = (const float*)d_in[0];
    const float* s0     = (const float*)d_in[1];
    const float* fc1_w  = (const float*)d_in[2];
    const float* fc1_b  = (const float*)d_in[3];
    const float* fc2_w  = (const float*)d_in[4];
    const float* fc2_b  = (const float*)d_in[5];
    const float* rc1_w  = (const float*)d_in[6];
    const float* rc1_b  = (const float*)d_in[7];
    const float* rc2_w  = (const float*)d_in[8];
    const float* rc2_b  = (const float*)d_in[9];
    const float* rc3_w  = (const float*)d_in[10];
    const float* rc3_b  = (const float*)d_in[11];
    const float* rr1_w  = (const float*)d_in[12];
    const float* rr1_b  = (const float*)d_in[13];
    const float* rr2_w  = (const float*)d_in[14];
    const float* rr2_b  = (const float*)d_in[15];
    const float* rr3_w  = (const float*)d_in[16];
    const float* rr3_b  = (const float*)d_in[17];
    float* out = (float*)d_out;

    int B = in_sizes[0] / 2;       // rows (4194304)
    int NW = B / 128;              // 128 rows per wave
    int block = 256;               // 4 waves per block
    int grid = (NW + 3) / 4;
    rollout_kernel<<<grid, block, 0, stream>>>(
        s_star, s0, fc1_w, fc1_b, fc2_w, fc2_b,
        rc1_w, rc1_b, rc2_w, rc2_b, rc3_w, rc3_b,
        rr1_w, rr1_b, rr2_w, rr2_b, rr3_w, rr3_b,
        out, NW);
}